// Round 8
// baseline (513.602 us; speedup 1.0000x reference)
//
#include <hip/hip_runtime.h>
#include <hip/hip_bf16.h>
#include <cstdint>

#define AS1 __attribute__((address_space(1)))
#define AS3 __attribute__((address_space(3)))

typedef __bf16 bf16x8 __attribute__((ext_vector_type(8)));
typedef float  f32x16 __attribute__((ext_vector_type(16)));

__device__ __forceinline__ void gld_lds16(const void* g, void* l) {
    __builtin_amdgcn_global_load_lds((const AS1 void*)g, (AS3 void*)l, 16, 0, 0);
}

// ---------------- Kernel 1: conv1 + relu -> channel-last padded bf16 h ----------------
// Also builds the bf16 GEMM A matrix (blocks < 1152).
// hl layout: [b][yy 0..29][xx 0..29][c 0..127], borders = 0.
__global__ __launch_bounds__(256) void k_conv1(const float* __restrict__ x,
                                               const float* __restrict__ base,
                                               const float* __restrict__ w2,
                                               __hip_bfloat16* __restrict__ hl,
                                               __hip_bfloat16* __restrict__ A) {
    int tid = threadIdx.x;

    if (blockIdx.x < 1152) {
        int i = blockIdx.x * 256 + tid;
        int r = i / 1152, k = i - r * 1152;
        int g = r >> 5, o2 = r & 31;
        int kk = k >> 7, cch = k & 127;
        int ky = kk / 3, kx = kk - ky * 3;
        int c2 = cch >> 3, hh = cch & 7;
        int gi = (g - hh) & 7;
        A[i] = __float2bfloat16(w2[((o2 * 16 + c2) * 8 + gi) * 9 + ky * 3 + kx]);
    }

    __shared__ float w1s[1152];
    if (tid < 128) {
        int g = tid >> 4, o = tid & 15;
        float th = 6.28318530717958647692f * (float)g / 8.0f;
        float c = cosf(th), s = sinf(th);
        for (int i = 0; i < 3; ++i) {
            float ys = (2.0f * i + 1.0f) / 3.0f - 1.0f;
            for (int j = 0; j < 3; ++j) {
                float xs = (2.0f * j + 1.0f) / 3.0f - 1.0f;
                float gx = c * xs - s * ys;
                float gy = s * xs + c * ys;
                float px = ((gx + 1.0f) * 3.0f - 1.0f) * 0.5f;
                float py = ((gy + 1.0f) * 3.0f - 1.0f) * 0.5f;
                float x0 = floorf(px), y0 = floorf(py);
                float wx = px - x0, wy = py - y0;
                int x0i = (int)x0, y0i = (int)y0;
                auto gat = [&](int yi, int xi) -> float {
                    bool v = (yi >= 0) && (yi < 3) && (xi >= 0) && (xi < 3);
                    int yc = min(max(yi, 0), 2), xc = min(max(xi, 0), 2);
                    return v ? base[o * 9 + yc * 3 + xc] : 0.0f;
                };
                w1s[tid * 9 + i * 3 + j] =
                      gat(y0i, x0i)         * (1.0f - wx) * (1.0f - wy)
                    + gat(y0i, x0i + 1)     * wx          * (1.0f - wy)
                    + gat(y0i + 1, x0i)     * (1.0f - wx) * wy
                    + gat(y0i + 1, x0i + 1) * wx          * wy;
            }
        }
    }
    __syncthreads();

    const int c0 = (tid & 15) * 8;
    float wreg[8][9];
#pragma unroll
    for (int cc = 0; cc < 8; ++cc)
#pragma unroll
        for (int k = 0; k < 9; ++k) wreg[cc][k] = w1s[(c0 + cc) * 9 + k];

    const int ps = tid >> 4;
    const int pbase = blockIdx.x * 64;    // grid 7200 exact -> 512*900 pixels

#pragma unroll
    for (int j = 0; j < 4; ++j) {
        int pi = pbase + j * 16 + ps;
        int xx = pi % 30; int t = pi / 30; int yy = t % 30; int b = t / 30;
        float acc[8] = {0.f,0.f,0.f,0.f,0.f,0.f,0.f,0.f};
        if (xx >= 1 && xx <= 28 && yy >= 1 && yy <= 28) {
            const float* xb = x + b * 784;
            int y = yy - 1, xc = xx - 1;
#pragma unroll
            for (int dy = -1; dy <= 1; ++dy) {
                int sy = y + dy;
#pragma unroll
                for (int dx = -1; dx <= 1; ++dx) {
                    int sx = xc + dx;
                    float xv = (sy >= 0 && sy < 28 && sx >= 0 && sx < 28) ? xb[sy * 28 + sx] : 0.0f;
                    int k = (dy + 1) * 3 + (dx + 1);
#pragma unroll
                    for (int cc = 0; cc < 8; ++cc) acc[cc] += xv * wreg[cc][k];
                }
            }
        }
        union { __hip_bfloat16 h[8]; float4 f4; } u;
#pragma unroll
        for (int cc = 0; cc < 8; ++cc) u.h[cc] = __float2bfloat16(fmaxf(acc[cc], 0.0f));
        *(float4*)(hl + (size_t)pi * 128 + c0) = u.f4;
    }
}

// ---------------- Kernel 2: conv2 implicit GEMM (32x32x16) + relu + pool -> p(bf16) ----
// Block tile: M=256 (ALL output rows) x N=128 pixels, BK=64, 18 stages.
// Wave tile: 128x64 = 4x2 frags of 32x32 -> 0.75 LDS frag-reads per MFMA (was 1.0).
// Dense-N: n = b*784 + y*28 + x; padded-30 hl absorbs (ky,kx) shifts.
// LDS swizzle (r&7)^((r>>3)&3) — verified conflict-free in R7.
__global__ __launch_bounds__(256) void k_conv2(const __hip_bfloat16* __restrict__ A,
                                               const __hip_bfloat16* __restrict__ hl,
                                               __hip_bfloat16* __restrict__ p) {
    __shared__ __align__(16) char smem[49152];   // As [256][64] bf16 | Bs [128][64] bf16

    const int tid  = threadIdx.x;
    const int lane = tid & 63;
    const int w    = tid >> 6;
    const int wr   = w >> 1, wc = w & 1;
    const int hi   = lane >> 5;           // K-half selector

    const int nt = blockIdx.x;            // grid 3136
    const int n0 = nt << 7;

    // staging constants: A 8 chunks/thread, B 4 chunks/thread (chunk = 1024 B = 8 rows)
    uint32_t aG[8], bG[4];
#pragma unroll
    for (int q = 0; q < 8; ++q) {
        int ch = w * 8 + q;                       // 0..31
        int rl = ch * 8 + (lane >> 3);            // A row 0..255
        int ca = (lane & 7) ^ (lane >> 3) ^ (ch & 3);
        aG[q] = (uint32_t)(rl * 2304 + ca * 16);
    }
#pragma unroll
    for (int q = 0; q < 4; ++q) {
        int ch = w * 4 + q;                       // 0..15
        int rl = ch * 8 + (lane >> 3);            // B col 0..127
        int ca = (lane & 7) ^ (lane >> 3) ^ (ch & 3);
        int n  = n0 + rl;
        int b  = n / 784; int rr = n - b * 784;
        int y  = rr / 28; int xx = rr - y * 28;
        bG[q]  = (uint32_t)(((b * 30 + y) * 30 + xx) * 256 + ca * 16);
    }

    // fragment-read constants
    uint32_t aro[4], bro[2]; int asw[4], bsw[2];
#pragma unroll
    for (int i = 0; i < 4; ++i) {
        int rl = 128 * wr + 32 * i + (lane & 31);
        aro[i] = (uint32_t)(rl * 128); asw[i] = (rl & 7) ^ ((rl >> 3) & 3);
    }
#pragma unroll
    for (int j = 0; j < 2; ++j) {
        int nl = 64 * wc + 32 * j + (lane & 31);
        bro[j] = (uint32_t)(32768 + nl * 128); bsw[j] = (nl & 7) ^ ((nl >> 3) & 3);
    }

    f32x16 acc[4][2];
#pragma unroll
    for (int i = 0; i < 4; ++i)
#pragma unroll
        for (int j = 0; j < 2; ++j) acc[i][j] = (f32x16)(0.0f);

    const char* Ab = (const char*)A;
    const char* Hb = (const char*)hl;

    for (int s = 0; s < 18; ++s) {
        int kk = s >> 1, half = s & 1;
        int ky = kk / 3, kx = kk - ky * 3;
        int aoff = kk * 256 + half * 128;
        int boff = (ky * 30 + kx) * 256 + half * 128;

        __syncthreads();
#pragma unroll
        for (int q = 0; q < 8; ++q)
            gld_lds16(Ab + aG[q] + aoff, smem + (w * 8 + q) * 1024);
#pragma unroll
        for (int q = 0; q < 4; ++q)
            gld_lds16(Hb + bG[q] + boff, smem + 32768 + (w * 4 + q) * 1024);
        __syncthreads();

#pragma unroll
        for (int kstep = 0; kstep < 4; ++kstep) {
            int cb = kstep * 2 + hi;
            bf16x8 af[4], bf[2];
#pragma unroll
            for (int i = 0; i < 4; ++i)
                af[i] = *(const bf16x8*)(smem + aro[i] + ((cb ^ asw[i]) * 16));
#pragma unroll
            for (int j = 0; j < 2; ++j)
                bf[j] = *(const bf16x8*)(smem + bro[j] + ((cb ^ bsw[j]) * 16));
#pragma unroll
            for (int i = 0; i < 4; ++i)
#pragma unroll
                for (int j = 0; j < 2; ++j)
                    acc[i][j] = __builtin_amdgcn_mfma_f32_32x32x16_bf16(af[i], bf[j], acc[i][j], 0, 0, 0);
        }
    }

    // epilogue: relu + mean over 8 consecutive M-rows; bf16 store.
#pragma unroll
    for (int i = 0; i < 4; ++i) {
#pragma unroll
        for (int j = 0; j < 2; ++j) {
            f32x16 v = acc[i][j];
#pragma unroll
            for (int q = 0; q < 4; ++q) {
                float s = fmaxf(v[4*q], 0.0f) + fmaxf(v[4*q+1], 0.0f)
                        + fmaxf(v[4*q+2], 0.0f) + fmaxf(v[4*q+3], 0.0f);
                s += __shfl_xor(s, 32, 64);
                if (hi == 0) {
                    int a = 16 * wr + 4 * i + q;
                    int n = n0 + 64 * wc + 32 * j + (lane & 31);
                    int b = n / 784; int rr = n - b * 784;
                    p[(b * 32 + a) * 784 + rr] = __float2bfloat16(s * 0.125f);
                }
            }
        }
    }
}

// ---------------- Kernel 3: FC — w staged in LDS, 16 k-splits x 32 batch-groups ----------------
__global__ __launch_bounds__(256) void k_fc(const __hip_bfloat16* __restrict__ p,
                                            const float* __restrict__ fw,
                                            const float* __restrict__ fb,
                                            float* __restrict__ out) {
    __shared__ float4 wl[3920];           // [10][392] float4
    const int bb = blockIdx.x >> 4;
    const int ks = blockIdx.x & 15;
    const int tid = threadIdx.x;
    const float4* w4 = (const float4*)fw;
    for (int i = tid; i < 3920; i += 256) {
        int c = i / 392, j = i - c * 392;
        wl[i] = w4[c * 6272 + ks * 392 + j];
    }
    __syncthreads();

    const int kl = tid & 15, bi = tid >> 4;
    const int b = bb * 16 + bi;
    const bf16x8* pb = (const bf16x8*)(p + (size_t)b * 25088 + ks * 1568);
    float acc[10] = {};
    for (int t = kl; t < 196; t += 16) {
        union { bf16x8 v; __hip_bfloat16 h[8]; } u;
        u.v = pb[t];
        float vf[8];
#pragma unroll
        for (int e = 0; e < 8; ++e) vf[e] = __bfloat162float(u.h[e]);
#pragma unroll
        for (int c = 0; c < 10; ++c) {
            float4 u0 = wl[c * 392 + 2 * t];
            float4 u1 = wl[c * 392 + 2 * t + 1];
            acc[c] += vf[0] * u0.x + vf[1] * u0.y + vf[2] * u0.z + vf[3] * u0.w
                    + vf[4] * u1.x + vf[5] * u1.y + vf[6] * u1.z + vf[7] * u1.w;
        }
    }
#pragma unroll
    for (int c = 0; c < 10; ++c) {
        float s = acc[c];
        s += __shfl_down(s, 8, 16);
        s += __shfl_down(s, 4, 16);
        s += __shfl_down(s, 2, 16);
        s += __shfl_down(s, 1, 16);
        if (kl == 0) {
            if (ks == 0) s += fb[c];
            atomicAdd(&out[b * 10 + c], s);
        }
    }
}

// ---------------- launch ----------------
extern "C" void kernel_launch(void* const* d_in, const int* in_sizes, int n_in,
                              void* d_out, int out_size, void* d_ws, size_t ws_size,
                              hipStream_t stream) {
    const float* x  = (const float*)d_in[0];
    const float* bw = (const float*)d_in[1];
    const float* w2 = (const float*)d_in[2];
    const float* fw = (const float*)d_in[3];
    const float* fb = (const float*)d_in[4];
    float* out = (float*)d_out;
    char* ws = (char*)d_ws;

    __hip_bfloat16* Amat = (__hip_bfloat16*)(ws + 4608);
    __hip_bfloat16* hl   = (__hip_bfloat16*)(ws + 594432);
    __hip_bfloat16* p    = (__hip_bfloat16*)(ws + 118563328);

    hipMemsetAsync(d_out, 0, (size_t)out_size * sizeof(float), stream);
    k_conv1<<<7200, 256, 0, stream>>>(x, bw, w2, hl, Amat);
    k_conv2<<<3136, 256, 0, stream>>>(Amat, hl, p);
    k_fc   <<<512,  256, 0, stream>>>(p, fw, fb, out);
}